// Round 7
// baseline (138.863 us; speedup 1.0000x reference)
//
#include <hip/hip_runtime.h>

#define BATCH 8
#define CH 512
#define C16 32
#define W 64
#define HWSZ 4096   // 64*64
#define NCH 4096    // BATCH*CH
#define LDS_STRIDE 68  // 64 + 4 pad (hs plane)
#define CPB 4          // channels per block in fused kernel
#define NBLK (NCH / CPB)

#define NEG_INF (-__builtin_inff())

// direct global->LDS DMA, 16B per lane, linear dest (base + lane*16)
#define GLOBAL_LOAD_LDS16(gsrc, ldst) \
  __builtin_amdgcn_global_load_lds((const __attribute__((address_space(1))) void*)(gsrc), \
                                   (__attribute__((address_space(3))) void*)(ldst), 16, 0, 0)

// ---------------- Kernel A: per-channel global average pool ----------------
__global__ __launch_bounds__(256) void gap_kernel(const float* __restrict__ x,
                                                  float* __restrict__ gap) {
    const int chan = blockIdx.x;
    const float* xp = x + (size_t)chan * HWSZ;
    const int t = threadIdx.x;
    float sum = 0.f;
#pragma unroll
    for (int j = 0; j < 4; ++j) {
        const float4 f = *(const float4*)(xp + t * 4 + j * 1024);
        sum += f.x + f.y + f.z + f.w;
    }
#pragma unroll
    for (int off = 32; off > 0; off >>= 1) sum += __shfl_down(sum, off, 64);
    __shared__ float ws[4];
    if ((t & 63) == 0) ws[t >> 6] = sum;
    __syncthreads();
    if (t == 0) {
        gap[chan] = (ws[0] + ws[1] + ws[2] + ws[3]) * (1.0f / HWSZ);
    }
}

// ---------------- Kernel B: fused SE-score + routed dual maxpool ----------------
__device__ __forceinline__ float4 max4(float4 a, float4 b) {
    return make_float4(fmaxf(a.x, b.x), fmaxf(a.y, b.y), fmaxf(a.z, b.z), fmaxf(a.w, b.w));
}
__device__ __forceinline__ float max3f(float a, float b, float c) {
    return fmaxf(fmaxf(a, b), c);  // clang folds to v_max3_f32
}

// level needed for half-width h: smallest L with 2^L >= h+1
constexpr int lvl(int h) { return h <= 0 ? 0 : (h <= 1 ? 1 : (h <= 3 ? 2 : 3)); }

// xs plane: 64 rows x 16 float4-blocks, XOR-swizzled: element (r, cb) lives at
// slot (r<<4) | (cb ^ (r&7)). Staged by pre-swizzling the global SOURCE address
// per lane (linear LDS dest, as global_load_lds requires); read with the same
// XOR. Involution -> bijective. Spreads the stride-64 column walk over 8 banks.
__device__ __forceinline__ void stage_xs(const float* __restrict__ xp,
                                         float4* __restrict__ xs4, int t) {
    const int lane = t & 63;
    const int m0 = (t >> 6) * 4;   // 4 DMA instructions per wave, 4 waves = 64 rows
#pragma unroll
    for (int k = 0; k < 4; ++k) {
        const int m = m0 + k;
        const int s = (m << 6) + lane;         // linear LDS slot this lane fills
        const int r = s >> 4;                  // row
        const int cb = (s & 15) ^ (r & 7);     // inverse-swizzled source block
        GLOBAL_LOAD_LDS16(xp + (r << 6) + (cb << 2), xs4 + (m << 6));
    }
}

// Horizontal: v[32] covers row positions [seg*16-8, seg*16+24); outputs 16 px
// of the half-Q window max (the Q+1 plane is derived in phase 2 by dilation).
template <int Q>
__device__ __forceinline__ void hpool_s(const float v[32], float os[16]) {
    constexpr int LS = lvl(Q);
    float m2[31], m4[29], m8[25];
    if constexpr (LS >= 1) {
#pragma unroll
        for (int j = 0; j < 31; ++j) m2[j] = fmaxf(v[j], v[j + 1]);
    }
    if constexpr (LS >= 2) {
#pragma unroll
        for (int j = 0; j < 29; ++j) m4[j] = fmaxf(m2[j], m2[j + 2]);
    }
    if constexpr (LS >= 3) {
#pragma unroll
        for (int j = 0; j < 25; ++j) m8[j] = fmaxf(m4[j], m4[j + 4]);
    }
#pragma unroll
    for (int i = 0; i < 16; ++i) {
        const int pos = 8 + i;
        constexpr int P = 1 << LS;
        const int a = pos - Q, b = pos + Q - P + 1;
        if constexpr (LS == 0) os[i] = v[pos];
        else if constexpr (LS == 1) os[i] = fmaxf(m2[a], m2[b]);
        else if constexpr (LS == 2) os[i] = fmaxf(m4[a], m4[b]);
        else os[i] = fmaxf(m8[a], m8[b]);
    }
}

// Phase 1: window + residual reads from swizzled xs, horizontal pool into hs.
template <int Q>
__device__ __forceinline__ void phase1_xs(const float4* __restrict__ xs4, float* hs,
                                          int r, int seg, float4 xv[4], int cg, int y0) {
    float v[32];
#pragma unroll
    for (int j = 0; j < 8; ++j) {
        const int p = seg * 16 - 8 + j * 4;
        if (p >= 0 && p < W) {
            const float4 f = xs4[(r << 4) | ((p >> 2) ^ (r & 7))];
            v[4*j] = f.x; v[4*j+1] = f.y; v[4*j+2] = f.z; v[4*j+3] = f.w;
        } else {
            v[4*j] = NEG_INF; v[4*j+1] = NEG_INF; v[4*j+2] = NEG_INF; v[4*j+3] = NEG_INF;
        }
    }
    // residual for THIS thread's phase-2 tile, read now so xs is dead after P1
#pragma unroll
    for (int i = 0; i < 4; ++i) {
        const int rr = y0 + i;
        xv[i] = xs4[(rr << 4) | (cg ^ (rr & 7))];
    }
    float os[16];
    hpool_s<Q>(v, os);
    float* hsp = hs + r * LDS_STRIDE + seg * 16;
#pragma unroll
    for (int j = 0; j < 4; ++j) {
        *(float4*)(hsp + 4 * j) = make_float4(os[4*j], os[4*j+1], os[4*j+2], os[4*j+3]);
    }
}

// Phase 2: LDS reads + shared vertical pyramid.
// vs4 = final s-branch; pre4 = b-branch before horizontal +-1 dilation
// (dilation commutes with the vertical max).
template <int Q>
__device__ __forceinline__ void phase2(const float* hs, int x0, int y0,
                                       float4 vs4[4], float4 pre4[4]) {
    constexpr int LS = lvl(Q);
    constexpr int LB = lvl(Q + 1);  // LB >= LS always
    float4 v[16];
#pragma unroll
    for (int j = 0; j < 16; ++j) {
        int row = y0 - 6 + j;
        row = row < 0 ? 0 : (row > 63 ? 63 : row);  // clamp == SAME pad for max
        v[j] = *(const float4*)(hs + row * LDS_STRIDE + x0);
    }
    float4 m2[15], m4[13], m8[9];
    if constexpr (LB >= 1) {
#pragma unroll
        for (int j = 0; j < 15; ++j) m2[j] = max4(v[j], v[j + 1]);
    }
    if constexpr (LB >= 2) {
#pragma unroll
        for (int j = 0; j < 13; ++j) m4[j] = max4(m2[j], m2[j + 2]);
    }
    if constexpr (LB >= 3) {
#pragma unroll
        for (int j = 0; j < 9; ++j) m8[j] = max4(m4[j], m4[j + 4]);
    }
#pragma unroll
    for (int i = 0; i < 4; ++i) {
        const int pos = 6 + i;
        {   // s branch: half Q at level LS
            constexpr int P = 1 << LS;
            const int a = pos - Q, b = pos + Q - P + 1;
            if constexpr (LS == 0) vs4[i] = v[pos];
            else if constexpr (LS == 1) vs4[i] = max4(m2[a], m2[b]);
            else if constexpr (LS == 2) vs4[i] = max4(m4[a], m4[b]);
            else vs4[i] = max4(m8[a], m8[b]);
        }
        {   // b branch pre: half Q+1 at level LB (same pyramid!)
            constexpr int HH = Q + 1;
            constexpr int P = 1 << LB;
            const int a = pos - HH, b = pos + HH - P + 1;
            if constexpr (LB == 1) pre4[i] = max4(m2[a], m2[b]);
            else if constexpr (LB == 2) pre4[i] = max4(m4[a], m4[b]);
            else pre4[i] = max4(m8[a], m8[b]);
        }
    }
}

// Q-independent epilogue: horizontal +-1 dilation of pre4 via lane shuffles,
// bilinear blend, residual add, store.
__device__ __forceinline__ void dilate_store(const float4 vs4[4], const float4 pre4[4],
                                             const float4 xv[4], float fb, float fs,
                                             float* __restrict__ op, int cg, int x0, int y0) {
#pragma unroll
    for (int i = 0; i < 4; ++i) {
        const float4 pre = pre4[i];
        float lp = __shfl_up(pre.w, 1);    // col x0-1 (left lane's .w)
        float rp = __shfl_down(pre.x, 1);  // col x0+4 (right lane's .x)
        if (cg == 0) lp = pre.x;           // clamp at image edge (SAME pad)
        if (cg == 15) rp = pre.w;
        float4 vb;
        vb.x = max3f(lp,    pre.x, pre.y);
        vb.y = max3f(pre.x, pre.y, pre.z);
        vb.z = max3f(pre.y, pre.z, pre.w);
        vb.w = max3f(pre.z, pre.w, rp);
        float4 o;
        o.x = fb * vb.x + fs * vs4[i].x + xv[i].x;
        o.y = fb * vb.y + fs * vs4[i].y + xv[i].y;
        o.z = fb * vb.z + fs * vs4[i].z + xv[i].z;
        o.w = fb * vb.w + fs * vs4[i].w + xv[i].w;
        *(float4*)(op + (y0 + i) * W + x0) = o;
    }
}

#define P1(QV) case QV: phase1_xs<QV>(xs4, hs, r, seg, xv, cg, y0); break;
#define P2(QV) case QV: phase2<QV>(hs, x0, y0, vs4, pre4); break;

// One block = CPB consecutive channels (same batch since CPB | CH).
// Per-channel critical chain is pure LDS+VALU: next channel's x is DMA'd into
// the swizzled xs plane during the CURRENT channel's phase-2 compute, so the
// phase-end barrier drains loads that already had a full phase of flight.
__global__ __launch_bounds__(256, 4) void score_pool_kernel(
        const float* __restrict__ x,
        const float* __restrict__ gap,
        const float* __restrict__ w1, const float* __restrict__ b1,
        const float* __restrict__ w2, const float* __restrict__ b2,
        float* __restrict__ out) {
    __shared__ float hs[64 * LDS_STRIDE];  // 17,408 B
    __shared__ float4 xs4[1024];           // 16,384 B swizzled x plane
    __shared__ float partial[C16][9];      // +1 pad
    __shared__ float hmid[C16];

    const int c0   = blockIdx.x * CPB;
    const int bidx = c0 >> 9;              // batch
    const int cch0 = c0 & 511;             // first channel within batch
    const int t = threadIdx.x;

    // stage channel 0 immediately — flies under the score phase
    stage_xs(x + (size_t)c0 * HWSZ, xs4, t);

    // ---- score phase: hmid = relu(w1 . gap + b1) ----
    // gap read DIRECT from global (16 KB, L2-hot, 8-lane broadcast) — no g[]
    // staging barrier, so the ch0 DMA gets ~the whole matmul as latency cover.
    {
        const int e = t >> 3, l = t & 7;
        const float* w1p = w1 + e * CH + l;
        const float* gp  = gap + bidx * CH + l;
        float p = 0.f;
#pragma unroll
        for (int k = 0; k < 64; ++k) p += gp[8 * k] * w1p[8 * k];
        partial[e][l] = p;
    }
    __syncthreads();
    if (t < C16) {
        float acc = b1[t];
#pragma unroll
        for (int j = 0; j < 8; ++j) acc += partial[t][j];
        hmid[t] = fmaxf(acc, 0.f);
    }
    __syncthreads();   // hmid ready; ch0 xs fully staged (vmcnt drained pre-barrier)

    const int r = t >> 2, seg = t & 3;
    const int cg = t & 15, rb = t >> 4;
    const int x0 = cg * 4, y0 = rb * 4;

    // ---- pool phase: CPB channels through the shared planes ----
    for (int ci = 0; ci < CPB; ++ci) {
        const int chan = c0 + ci;
        float* op = out + (size_t)chan * HWSZ;

        // per-channel score from LDS-resident hmid (block-uniform -> scalar)
        const int c = cch0 + ci;
        float sacc = b2[c];
#pragma unroll
        for (int e2 = 0; e2 < C16; ++e2) sacc += hmid[e2] * w2[c * C16 + e2];
        const float s = fmaxf(sacc, 0.f);  // expend_num_relu
        int q = (int)floorf(s);
        q = q < 0 ? 0 : (q > 5 ? 5 : q);
        const float fb = s - (float)q;        // weight on larger kernel
        const float fs = (float)(q + 1) - s;  // weight on smaller kernel

        float4 xv[4], vs4[4], pre4[4];
        switch (q) { P1(0) P1(1) P1(2) P1(3) P1(4) default: phase1_xs<5>(xs4, hs, r, seg, xv, cg, y0); }
        __syncthreads();   // hs ready; xs dead (windows AND residual consumed)

        if (ci < CPB - 1) stage_xs(x + (size_t)(chan + 1) * HWSZ, xs4, t);  // overlap with P2

        switch (q) { P2(0) P2(1) P2(2) P2(3) P2(4) default: phase2<5>(hs, x0, y0, vs4, pre4); }
        dilate_store(vs4, pre4, xv, fb, fs, op, cg, x0, y0);
        __syncthreads();   // drains next-channel DMA (had all of P2 in flight) + hs reuse
    }
}

extern "C" void kernel_launch(void* const* d_in, const int* in_sizes, int n_in,
                              void* d_out, int out_size, void* d_ws, size_t ws_size,
                              hipStream_t stream) {
    const float* x  = (const float*)d_in[0];
    const float* w1 = (const float*)d_in[1];
    const float* b1 = (const float*)d_in[2];
    const float* w2 = (const float*)d_in[3];
    const float* b2 = (const float*)d_in[4];
    float* out = (float*)d_out;
    float* gap = (float*)d_ws;                 // NCH floats

    gap_kernel<<<NCH, 256, 0, stream>>>(x, gap);
    score_pool_kernel<<<NBLK, 256, 0, stream>>>(x, gap, w1, b1, w2, b2, out);
}

// Round 8
// 134.135 us; speedup vs baseline: 1.0352x; 1.0352x over previous
//
#include <hip/hip_runtime.h>

#define BATCH 8
#define CH 512
#define C16 32
#define W 64
#define HWSZ 4096   // 64*64
#define NCH 4096    // BATCH*CH
#define LDS_STRIDE 68  // 64 + 4 pad
#define CPB 2          // channels per block in fused kernel (2 -> grid 2048, ~7 blocks/CU)
#define NBLK (NCH / CPB)

#define NEG_INF (-__builtin_inff())

// ---------------- Kernel A: per-channel global average pool ----------------
__global__ __launch_bounds__(256) void gap_kernel(const float* __restrict__ x,
                                                  float* __restrict__ gap) {
    const int chan = blockIdx.x;
    const float* xp = x + (size_t)chan * HWSZ;
    const int t = threadIdx.x;
    float sum = 0.f;
#pragma unroll
    for (int j = 0; j < 4; ++j) {
        const float4 f = *(const float4*)(xp + t * 4 + j * 1024);
        sum += f.x + f.y + f.z + f.w;
    }
#pragma unroll
    for (int off = 32; off > 0; off >>= 1) sum += __shfl_down(sum, off, 64);
    __shared__ float ws[4];
    if ((t & 63) == 0) ws[t >> 6] = sum;
    __syncthreads();
    if (t == 0) {
        gap[chan] = (ws[0] + ws[1] + ws[2] + ws[3]) * (1.0f / HWSZ);
    }
}

// ---------------- Kernel B: fused SE-score + routed dual maxpool ----------------
__device__ __forceinline__ float4 max4(float4 a, float4 b) {
    return make_float4(fmaxf(a.x, b.x), fmaxf(a.y, b.y), fmaxf(a.z, b.z), fmaxf(a.w, b.w));
}
__device__ __forceinline__ float max3f(float a, float b, float c) {
    return fmaxf(fmaxf(a, b), c);  // clang folds to v_max3_f32
}

// level needed for half-width h: smallest L with 2^L >= h+1
constexpr int lvl(int h) { return h <= 0 ? 0 : (h <= 1 ? 1 : (h <= 3 ? 2 : 3)); }

// Horizontal: v[32] covers row positions [seg*16-8, seg*16+24); outputs 16 px
// of the half-Q window max (the Q+1 plane is derived in phase 2 by dilation).
template <int Q>
__device__ __forceinline__ void hpool_s(const float v[32], float os[16]) {
    constexpr int LS = lvl(Q);
    float m2[31], m4[29], m8[25];
    if constexpr (LS >= 1) {
#pragma unroll
        for (int j = 0; j < 31; ++j) m2[j] = fmaxf(v[j], v[j + 1]);
    }
    if constexpr (LS >= 2) {
#pragma unroll
        for (int j = 0; j < 29; ++j) m4[j] = fmaxf(m2[j], m2[j + 2]);
    }
    if constexpr (LS >= 3) {
#pragma unroll
        for (int j = 0; j < 25; ++j) m8[j] = fmaxf(m4[j], m4[j + 4]);
    }
#pragma unroll
    for (int i = 0; i < 16; ++i) {
        const int pos = 8 + i;
        constexpr int P = 1 << LS;
        const int a = pos - Q, b = pos + Q - P + 1;
        if constexpr (LS == 0) os[i] = v[pos];
        else if constexpr (LS == 1) os[i] = fmaxf(m2[a], m2[b]);
        else if constexpr (LS == 2) os[i] = fmaxf(m4[a], m4[b]);
        else os[i] = fmaxf(m8[a], m8[b]);
    }
}

// Phase 1: horizontal pool into the shared hs plane.
template <int Q>
__device__ __forceinline__ void phase1(const float v[32], float* hs, int r, int seg) {
    float os[16];
    hpool_s<Q>(v, os);
    float* hsp = hs + r * LDS_STRIDE + seg * 16;
#pragma unroll
    for (int j = 0; j < 4; ++j) {
        *(float4*)(hsp + 4 * j) = make_float4(os[4*j], os[4*j+1], os[4*j+2], os[4*j+3]);
    }
}

// Phase 2: LDS reads + shared vertical pyramid.
// vs4 = final s-branch values; pre4 = b-branch before horizontal +-1 dilation
// (dilation commutes with the vertical max).
template <int Q>
__device__ __forceinline__ void phase2(const float* hs, int x0, int y0,
                                       float4 vs4[4], float4 pre4[4]) {
    constexpr int LS = lvl(Q);
    constexpr int LB = lvl(Q + 1);  // LB >= LS always
    float4 v[16];
#pragma unroll
    for (int j = 0; j < 16; ++j) {
        int row = y0 - 6 + j;
        row = row < 0 ? 0 : (row > 63 ? 63 : row);  // clamp == SAME pad for max
        v[j] = *(const float4*)(hs + row * LDS_STRIDE + x0);
    }
    float4 m2[15], m4[13], m8[9];
    if constexpr (LB >= 1) {
#pragma unroll
        for (int j = 0; j < 15; ++j) m2[j] = max4(v[j], v[j + 1]);
    }
    if constexpr (LB >= 2) {
#pragma unroll
        for (int j = 0; j < 13; ++j) m4[j] = max4(m2[j], m2[j + 2]);
    }
    if constexpr (LB >= 3) {
#pragma unroll
        for (int j = 0; j < 9; ++j) m8[j] = max4(m4[j], m4[j + 4]);
    }
#pragma unroll
    for (int i = 0; i < 4; ++i) {
        const int pos = 6 + i;
        {   // s branch: half Q at level LS
            constexpr int P = 1 << LS;
            const int a = pos - Q, b = pos + Q - P + 1;
            if constexpr (LS == 0) vs4[i] = v[pos];
            else if constexpr (LS == 1) vs4[i] = max4(m2[a], m2[b]);
            else if constexpr (LS == 2) vs4[i] = max4(m4[a], m4[b]);
            else vs4[i] = max4(m8[a], m8[b]);
        }
        {   // b branch pre: half Q+1 at level LB (same pyramid!)
            constexpr int HH = Q + 1;
            constexpr int P = 1 << LB;
            const int a = pos - HH, b = pos + HH - P + 1;
            if constexpr (LB == 1) pre4[i] = max4(m2[a], m2[b]);
            else if constexpr (LB == 2) pre4[i] = max4(m4[a], m4[b]);
            else pre4[i] = max4(m8[a], m8[b]);
        }
    }
}

// Q-independent epilogue: horizontal +-1 dilation of pre4 via lane shuffles,
// bilinear blend, residual add, store.
__device__ __forceinline__ void dilate_store(const float4 vs4[4], const float4 pre4[4],
                                             const float4 xv[4], float fb, float fs,
                                             float* __restrict__ op, int cg, int x0, int y0) {
#pragma unroll
    for (int i = 0; i < 4; ++i) {
        const float4 pre = pre4[i];
        float lp = __shfl_up(pre.w, 1);    // col x0-1 (left lane's .w)
        float rp = __shfl_down(pre.x, 1);  // col x0+4 (right lane's .x)
        if (cg == 0) lp = pre.x;           // clamp at image edge (SAME pad)
        if (cg == 15) rp = pre.w;
        float4 vb;
        vb.x = max3f(lp,    pre.x, pre.y);
        vb.y = max3f(pre.x, pre.y, pre.z);
        vb.z = max3f(pre.y, pre.z, pre.w);
        vb.w = max3f(pre.z, pre.w, rp);
        float4 o;
        o.x = fb * vb.x + fs * vs4[i].x + xv[i].x;
        o.y = fb * vb.y + fs * vs4[i].y + xv[i].y;
        o.z = fb * vb.z + fs * vs4[i].z + xv[i].z;
        o.w = fb * vb.w + fs * vs4[i].w + xv[i].w;
        *(float4*)(op + (y0 + i) * W + x0) = o;
    }
}

__device__ __forceinline__ void load_window(const float* __restrict__ rowp, int seg,
                                            float v[32]) {
#pragma unroll
    for (int j = 0; j < 8; ++j) {
        const int p = seg * 16 - 8 + j * 4;
        if (p >= 0 && p < W) {
            const float4 f = *(const float4*)(rowp + p);
            v[4*j] = f.x; v[4*j+1] = f.y; v[4*j+2] = f.z; v[4*j+3] = f.w;
        } else {
            v[4*j] = NEG_INF; v[4*j+1] = NEG_INF; v[4*j+2] = NEG_INF; v[4*j+3] = NEG_INF;
        }
    }
}

#define P1(QV) case QV: phase1<QV>(v, hs, r, seg); break;
#define P2(QV) case QV: phase2<QV>(hs, x0, y0, vs4, pre4); break;

// One block = CPB consecutive channels (same batch since CPB | CH).
// Score phase recomputed per block from gap (conflict-free, coalesced w1):
// only hmid[32] is a true cross-channel dependency; per-channel s is 32 FMAs.
// CPB=2 -> grid 2048: ~7 resident blocks/CU (LDS-capped) for inter-block TLP,
// which R7 showed is what actually hides the global-load latency here.
__global__ __launch_bounds__(256, 4) void score_pool_kernel(
        const float* __restrict__ x,
        const float* __restrict__ gap,
        const float* __restrict__ w1, const float* __restrict__ b1,
        const float* __restrict__ w2, const float* __restrict__ b2,
        float* __restrict__ out) {
    __shared__ float hs[64 * LDS_STRIDE];  // 17,408 B
    __shared__ float g[CH];
    __shared__ float partial[C16][9];      // +1 pad (addr=9e+l, gcd(9,32)=1 -> bank-spread)
    __shared__ float hmid[C16];

    const int c0   = blockIdx.x * CPB;     // first global channel of this block
    const int bidx = c0 >> 9;              // batch
    const int cch0 = c0 & 511;             // first channel within batch
    const int t = threadIdx.x;

    // ---- score phase: hmid = relu(w1 . gap + b1), conflict-free banking ----
    g[t]       = gap[bidx * CH + t];
    g[t + 256] = gap[bidx * CH + t + 256];
    __syncthreads();
    {
        // e = output row (0..31), l = 8-way partial lane. LDS reads g[l+8k]:
        // 8 distinct CONSECUTIVE addresses per wave -> distinct banks, 8-lane
        // broadcast each -> conflict-free. w1 reads: 8 lanes x 32 B contiguous.
        const int e = t >> 3, l = t & 7;
        const float* w1p = w1 + e * CH + l;
        float p = 0.f;
#pragma unroll
        for (int k = 0; k < 64; ++k) p += g[l + 8 * k] * w1p[8 * k];
        partial[e][l] = p;
    }
    __syncthreads();
    if (t < C16) {
        float acc = b1[t];
#pragma unroll
        for (int j = 0; j < 8; ++j) acc += partial[t][j];
        hmid[t] = fmaxf(acc, 0.f);
    }
    __syncthreads();

    const int r = t >> 2, seg = t & 3;
    const int cg = t & 15, rb = t >> 4;
    const int x0 = cg * 4, y0 = rb * 4;

    // ---- pool phase: CPB channels sequential through the shared hs plane ----
    for (int ci = 0; ci < CPB; ++ci) {
        const int chan = c0 + ci;
        const float* xp = x + (size_t)chan * HWSZ;
        float* op = out + (size_t)chan * HWSZ;

        // issue window loads first; s-compute (uniform scalar ops) overlaps
        float v[32];
        load_window(xp + r * W, seg, v);

        // per-channel score from LDS-resident hmid (block-uniform -> scalar)
        const int c = cch0 + ci;
        float sacc = b2[c];
#pragma unroll
        for (int e2 = 0; e2 < C16; ++e2) sacc += hmid[e2] * w2[c * C16 + e2];
        const float s = fmaxf(sacc, 0.f);  // expend_num_relu
        int q = (int)floorf(s);
        q = q < 0 ? 0 : (q > 5 ? 5 : q);
        const float fb = s - (float)q;        // weight on larger kernel
        const float fs = (float)(q + 1) - s;  // weight on smaller kernel

        switch (q) { P1(0) P1(1) P1(2) P1(3) P1(4) default: phase1<5>(v, hs, r, seg); }
        __syncthreads();

        float4 xv[4];
#pragma unroll
        for (int i = 0; i < 4; ++i) xv[i] = *(const float4*)(xp + (y0 + i) * W + x0);
        float4 vs4[4], pre4[4];
        switch (q) { P2(0) P2(1) P2(2) P2(3) P2(4) default: phase2<5>(hs, x0, y0, vs4, pre4); }
        dilate_store(vs4, pre4, xv, fb, fs, op, cg, x0, y0);
        __syncthreads();  // hs reads done -> plane reusable next iteration
    }
}

extern "C" void kernel_launch(void* const* d_in, const int* in_sizes, int n_in,
                              void* d_out, int out_size, void* d_ws, size_t ws_size,
                              hipStream_t stream) {
    const float* x  = (const float*)d_in[0];
    const float* w1 = (const float*)d_in[1];
    const float* b1 = (const float*)d_in[2];
    const float* w2 = (const float*)d_in[3];
    const float* b2 = (const float*)d_in[4];
    float* out = (float*)d_out;
    float* gap = (float*)d_ws;                 // NCH floats

    gap_kernel<<<NCH, 256, 0, stream>>>(x, gap);
    score_pool_kernel<<<NBLK, 256, 0, stream>>>(x, gap, w1, b1, w2, b2, out);
}